// Round 11
// baseline (1169.408 us; speedup 1.0000x reference)
//
#include <hip/hip_runtime.h>

#define DIM 1024
#define NKN 65536
#define TOK 4096
#define CK 20
#define FK 10
#define RNK 128
#define CAP 256
#define NCHUNK 512   // 65536 / 128 cols per GEMM block

typedef __bf16 v8bf __attribute__((ext_vector_type(8)));
typedef float v4f __attribute__((ext_vector_type(4)));

#define AS1 __attribute__((address_space(1)))
#define AS3 __attribute__((address_space(3)))

__device__ __forceinline__ unsigned short f2bf(float f) {
  // round-to-nearest-even fp32 -> bf16 (finite inputs only)
  unsigned u = __builtin_bit_cast(unsigned, f);
  u += 0x7FFFu + ((u >> 16) & 1u);
  return (unsigned short)(u >> 16);
}
__device__ __forceinline__ unsigned short bf2key(unsigned short b) {
  // monotone order-preserving key for bf16 bits
  return (b & 0x8000) ? (unsigned short)(~b) : (unsigned short)(b | 0x8000);
}

// ---------------------------------------------------------------------------
// K1: transpose W_router [DIM][NKN] -> WT fp32 [NKN][DIM] (NT stores; read
// much later by rescore) and WT bf16 [NKN][DIM] (cached; read next by gemm).
// ---------------------------------------------------------------------------
__global__ __launch_bounds__(256) void k_transpose(const float* __restrict__ W,
                                                   float* __restrict__ WT,
                                                   unsigned short* __restrict__ WTb) {
  __shared__ float tile[32][33];
  const int n0 = (blockIdx.x & 2047) << 5;
  const int d0 = (blockIdx.x >> 11) << 5;
  const int c = threadIdx.x & 31, r0 = threadIdx.x >> 5;
#pragma unroll
  for (int i = 0; i < 4; i++) {
    int r = r0 + i * 8;
    tile[r][c] = W[(size_t)(d0 + r) * NKN + n0 + c];
  }
  __syncthreads();
#pragma unroll
  for (int i = 0; i < 4; i++) {
    int r = r0 + i * 8;
    float v = tile[c][r];  // = W[d0+c][n0+r]
    size_t o = (size_t)(n0 + r) * DIM + d0 + c;
    __builtin_nontemporal_store(v, &WT[o]);
    WTb[o] = f2bf(v);
  }
}

// ---------------------------------------------------------------------------
// K1b: convert x fp32 -> bf16
// ---------------------------------------------------------------------------
__global__ __launch_bounds__(256) void k_cvt_x(const float* __restrict__ x,
                                               unsigned short* __restrict__ xb) {
  const int i = blockIdx.x * 256 + threadIdx.x;
  const float4 v = reinterpret_cast<const float4*>(x)[i];
  ushort4 o;
  o.x = f2bf(v.x); o.y = f2bf(v.y); o.z = f2bf(v.z); o.w = f2bf(v.w);
  reinterpret_cast<ushort4*>(xb)[i] = o;
}

// ---------------------------------------------------------------------------
// K2: bf16 MFMA GEMM (r9 geometry, proven 858 TF) + NT logit stores (r11).
// 256x128 tile, BK=32, 512 threads = 8 waves (4M x 2N), per-wave C = 64x64
// -> acc 64 AGPR, VGPR ~60 -> 4 waves/SIMD = 2 blocks/CU.
// LDS: 3-slot ring x 24 KB; prefetch dist 2; vmcnt(6)/(3)/(0); 2 barriers/tile.
// LDS swizzle (r9, measured 0 conflicts): phys 16B-slot = lq ^ ((row>>1)&3).
// r11: Lg written NON-TEMPORAL -- 512 MB stream was thrashing L3 and
// evicting the shared B panels (FETCH 634 MB vs 136 ideal); Lg is re-read
// only ~37 MB in k_pickscore, so caching it is pure pollution.
// Fused epilogue: per-row max over the block's 128 cols -> CmaxT[nb][row].
// ---------------------------------------------------------------------------
__global__ __launch_bounds__(512, 4) void k_gemm(const unsigned short* __restrict__ A,
                                                 const unsigned short* __restrict__ Bt,
                                                 unsigned short* __restrict__ Lg,
                                                 unsigned short* __restrict__ CmaxT) {
  __shared__ __align__(16) char lds[73728];  // ring[3]: {A 16 KB, B 8 KB}
  const int tid = threadIdx.x;
  const int lane = tid & 63, wid = tid >> 6;
  const int wm = wid >> 1, wn = wid & 1;
  const int mb = blockIdx.x & 15, nb = blockIdx.x >> 4;  // m-fast: B-panel reuse
  const int m0 = mb << 8, n0 = nb << 7;
  const int rm = lane & 15, lq = lane >> 4;
  v4f acc[4][4] = {};

  const int u8 = (((tid & 3) ^ ((tid >> 3) & 3)) << 3);
  const unsigned short* aSrc = A + (size_t)(m0 + (tid >> 2)) * DIM + u8;
  const unsigned short* bSrc = Bt + (size_t)(n0 + (tid >> 2)) * DIM + u8;

  const int sx = ((lq ^ ((rm >> 1) & 3)) << 4);
  const int aOff = (wm * 64 + rm) * 64 + sx;           // + fr*1024
  const int bOff = 16384 + (wn * 64 + rm) * 64 + sx;   // + nf*1024

#define STAGE(SLOT, KT) do { \
    char* _b = lds + (SLOT) * 24576 + tid * 16; \
    __builtin_amdgcn_global_load_lds((const AS1 void*)(aSrc + (KT)),             (AS3 void*)(_b),         16, 0, 0); \
    __builtin_amdgcn_global_load_lds((const AS1 void*)(aSrc + (KT) + 128 * DIM), (AS3 void*)(_b + 8192),  16, 0, 0); \
    __builtin_amdgcn_global_load_lds((const AS1 void*)(bSrc + (KT)),             (AS3 void*)(_b + 16384), 16, 0, 0); \
  } while (0)

#define TILE(T, VM, DOSTAGE) do { \
    if (DOSTAGE) STAGE(((T) + 2) % 3, ((T) + 2) * 32); \
    asm volatile("s_waitcnt vmcnt(" VM ")" ::: "memory"); \
    __builtin_amdgcn_s_barrier(); \
    const char* sb = lds + ((T) % 3) * 24576; \
    v8bf a0 = *(const v8bf*)(sb + aOff); \
    v8bf a1 = *(const v8bf*)(sb + aOff + 1024); \
    v8bf a2 = *(const v8bf*)(sb + aOff + 2048); \
    v8bf a3 = *(const v8bf*)(sb + aOff + 3072); \
    v8bf b0 = *(const v8bf*)(sb + bOff); \
    v8bf b1 = *(const v8bf*)(sb + bOff + 1024); \
    v8bf b2 = *(const v8bf*)(sb + bOff + 2048); \
    v8bf b3 = *(const v8bf*)(sb + bOff + 3072); \
    __builtin_amdgcn_s_setprio(1); \
    _Pragma("unroll") for (int nf = 0; nf < 4; ++nf) { \
      v8bf bb = (nf == 0) ? b0 : (nf == 1) ? b1 : (nf == 2) ? b2 : b3; \
      acc[0][nf] = __builtin_amdgcn_mfma_f32_16x16x32_bf16(a0, bb, acc[0][nf], 0, 0, 0); \
      acc[1][nf] = __builtin_amdgcn_mfma_f32_16x16x32_bf16(a1, bb, acc[1][nf], 0, 0, 0); \
      acc[2][nf] = __builtin_amdgcn_mfma_f32_16x16x32_bf16(a2, bb, acc[2][nf], 0, 0, 0); \
      acc[3][nf] = __builtin_amdgcn_mfma_f32_16x16x32_bf16(a3, bb, acc[3][nf], 0, 0, 0); \
    } \
    __builtin_amdgcn_s_setprio(0); \
    __builtin_amdgcn_s_barrier(); \
  } while (0)

  STAGE(0, 0);
  STAGE(1, 32);

  for (int t = 0; t < 30; ++t) {
    TILE(t, "6", true);
  }
  TILE(30, "3", false);
  TILE(31, "0", false);
#undef TILE
#undef STAGE

  // ---- epilogue ----
  // C/D layout (verified m89/m91): n = rm, m = lq*4 + reg
  const int mr = lq * 4;
  float rmax[4][4];
#pragma unroll
  for (int fr = 0; fr < 4; ++fr) {
#pragma unroll
    for (int r = 0; r < 4; ++r) {
      float mx = acc[fr][0][r];
#pragma unroll
      for (int nf = 1; nf < 4; ++nf) mx = fmaxf(mx, acc[fr][nf][r]);
      rmax[fr][r] = mx;
    }
#pragma unroll
    for (int nf = 0; nf < 4; ++nf) {
      const int mrow = m0 + wm * 64 + fr * 16 + mr;
      const int ncol = n0 + wn * 64 + nf * 16 + rm;
#pragma unroll
      for (int r = 0; r < 4; ++r)
        __builtin_nontemporal_store(f2bf(acc[fr][nf][r]),
                                    &Lg[(size_t)(mrow + r) * NKN + ncol]);
    }
  }
#pragma unroll
  for (int fr = 0; fr < 4; ++fr)
#pragma unroll
    for (int r = 0; r < 4; ++r) {
#pragma unroll
      for (int off = 1; off < 16; off <<= 1)
        rmax[fr][r] = fmaxf(rmax[fr][r], __shfl_xor(rmax[fr][r], off));
    }
  __syncthreads();
  float* smax = (float*)lds;  // [2][256]
  if (rm == 0) {
#pragma unroll
    for (int fr = 0; fr < 4; ++fr)
#pragma unroll
      for (int r = 0; r < 4; ++r)
        smax[wn * 256 + wm * 64 + fr * 16 + mr + r] = rmax[fr][r];
  }
  __syncthreads();
  if (tid < 256) {
    float v = fmaxf(smax[tid], smax[256 + tid]);
    CmaxT[(size_t)nb * TOK + m0 + tid] = bf2key(f2bf(v));
  }
}

// ---------------------------------------------------------------------------
// K3 (fused r11): pick candidates from chunk maxes + exact fp64 rescore +
// exact top-20. tau = 32nd-largest chunk-max key (exact); candidate set =
// {key >= tau} superset of bf16-top-32 superset of fp32-top-20 (margin
// ~14 sigma). Candidates never leave LDS.
// ---------------------------------------------------------------------------
__global__ __launch_bounds__(256) void k_pickscore(const unsigned short* __restrict__ CmaxT,
                                                   const unsigned short* __restrict__ Lg,
                                                   const float* __restrict__ x,
                                                   const float* __restrict__ WT,
                                                   int* __restrict__ coarse) {
  __shared__ unsigned short keys[NCHUNK];
  __shared__ int qlist[NCHUNK];
  __shared__ float xs[DIM];
  __shared__ double sc[CAP];
  __shared__ int ci[CAP];
  __shared__ int qn, scnt, bsS;
  const int t = blockIdx.x, tid = threadIdx.x;
  const int lane = tid & 63, w = tid >> 6;
  keys[tid] = CmaxT[(size_t)tid * TOK + t];
  keys[tid + 256] = CmaxT[(size_t)(tid + 256) * TOK + t];
  for (int i = tid; i < DIM; i += 256) xs[i] = x[(size_t)t * DIM + i];
  if (tid == 0) { qn = 0; scnt = 0; }
  __syncthreads();
  // tau = 32nd-largest chunk-max key (wave 0)
  if (w == 0) {
    int v[8];
#pragma unroll
    for (int j = 0; j < 8; j++) v[j] = keys[lane * 8 + j];
    int t32 = 0;
    for (int it = 0; it < 32; it++) {
      int lm = v[0];
#pragma unroll
      for (int j = 1; j < 8; j++) lm = max(lm, v[j]);
      int gm = lm;
#pragma unroll
      for (int off = 32; off > 0; off >>= 1) gm = max(gm, __shfl_xor(gm, off));
      unsigned long long msk = __ballot(lm == gm);
      if (lane == __ffsll((long long)msk) - 1) {
        bool done = false;
#pragma unroll
        for (int j = 0; j < 8; j++)
          if (!done && v[j] == gm) { v[j] = -1; done = true; }
      }
      t32 = gm;
    }
    if (lane == 0) bsS = t32;
  }
  __syncthreads();
  const int bs = bsS;
  for (int c = tid; c < NCHUNK; c += 256)
    if ((int)keys[c] >= bs) { int p = atomicAdd(&qn, 1); qlist[p] = c; }
  __syncthreads();
  const int nq = qn;
  const int sub = tid >> 7, e = tid & 127;
  for (int qi = sub; qi < nq; qi += 2) {
    const int col = qlist[qi] * 128 + e;
    unsigned short key = bf2key(Lg[(size_t)t * NKN + col]);
    if ((int)key >= bs) {
      int p = atomicAdd(&scnt, 1);
      if (p < CAP) ci[p] = col;
    }
  }
  __syncthreads();
  const int cnt = min(scnt, CAP);
  for (int i = tid; i < CAP; i += 256)
    if (i >= cnt) ci[i] = 0;
  for (int i = tid; i < CAP; i += 256) sc[i] = -1e300;
  __syncthreads();
  // exact fp64 rescore of candidates
  for (int c = w; c < cnt; c += 4) {
    const float* wr = WT + (size_t)ci[c] * DIM;
    double sacc = 0.0;
#pragma unroll 4
    for (int i = lane; i < DIM; i += 64) sacc += (double)xs[i] * (double)wr[i];
#pragma unroll
    for (int off = 32; off > 0; off >>= 1) sacc += __shfl_down(sacc, off);
    if (lane == 0) sc[c] = sacc;
  }
  __syncthreads();
  // exact top-20 (wave 0)
  if (w == 0) {
    double v[4];
    int ix[4];
#pragma unroll
    for (int j = 0; j < 4; j++) { v[j] = sc[lane + j * 64]; ix[j] = lane + j * 64; }
    for (int kk = 0; kk < CK; kk++) {
      double v1 = v[0]; int i1 = ix[0];
#pragma unroll
      for (int j = 1; j < 4; j++)
        if (v[j] > v1) { v1 = v[j]; i1 = ix[j]; }
#pragma unroll
      for (int off = 32; off > 0; off >>= 1) {
        double ov = __shfl_down(v1, off);
        int oi = __shfl_down(i1, off);
        if (ov > v1) { v1 = ov; i1 = oi; }
      }
      i1 = __shfl(i1, 0);
      if (lane == 0) coarse[(size_t)t * CK + kk] = ci[i1];
#pragma unroll
      for (int j = 0; j < 4; j++)
        if (i1 == ix[j]) v[j] = -1e300;
    }
  }
}

// ---------------------------------------------------------------------------
// K4 (fused r11): query = x @ W_enc computed in-kernel, then fine scores vs
// 20 candidates, top-10, softmax, weighted V blend.
// ---------------------------------------------------------------------------
__global__ __launch_bounds__(256) void k_fine(const float* __restrict__ x,
                                              const float* __restrict__ Wenc,
                                              const float* __restrict__ Kall,
                                              const float* __restrict__ Vall,
                                              const int* __restrict__ coarse,
                                              float* __restrict__ out) {
  __shared__ float xs[DIM];
  __shared__ float pq[2][RNK];
  __shared__ float qs[RNK];
  __shared__ float fsc[CK];
  __shared__ int gix[CK];
  __shared__ float wts[FK];
  __shared__ int fidx[FK];
  const int t = blockIdx.x, tid = threadIdx.x;
  const int lane = tid & 63, w = tid >> 6;
  // stage x row (vectorized)
  reinterpret_cast<float4*>(xs)[tid] = reinterpret_cast<const float4*>(x + (size_t)t * DIM)[tid];
  if (tid < CK) gix[tid] = coarse[(size_t)t * CK + tid];
  __syncthreads();
  // query: thread (j, half) computes partial dot over 512 d's
  {
    const int j = tid & 127, half = tid >> 7;
    float s = 0.f;
    const int d0 = half * 512;
#pragma unroll 8
    for (int d = 0; d < 512; d++)
      s = fmaf(xs[d0 + d], Wenc[(size_t)(d0 + d) * RNK + j], s);
    pq[half][j] = s;
  }
  __syncthreads();
  if (tid < RNK) qs[tid] = pq[0][tid] + pq[1][tid];
  __syncthreads();
  for (int c = w; c < CK; c += 4) {
    const float* kr = Kall + (size_t)gix[c] * RNK;
    float s = 0.f;
    s = fmaf(qs[lane], kr[lane], s);
    s = fmaf(qs[lane + 64], kr[lane + 64], s);
#pragma unroll
    for (int off = 32; off > 0; off >>= 1) s += __shfl_down(s, off);
    if (lane == 0) fsc[c] = s * 0.08838834764831843f;  // 1/sqrt(128)
  }
  __syncthreads();
  if (w == 0) {
    float vv = (lane < CK) ? fsc[lane] : -3e38f;
    float myv = -3e38f; int myp = 0;
    for (int kk = 0; kk < FK; kk++) {
      float v1 = vv; int p1 = lane;
#pragma unroll
      for (int off = 32; off > 0; off >>= 1) {
        float ov = __shfl_down(v1, off);
        int op = __shfl_down(p1, off);
        if (ov > v1) { v1 = ov; p1 = op; }
      }
      v1 = __shfl(v1, 0); p1 = __shfl(p1, 0);
      if (lane == kk) { myv = v1; myp = p1; }
      if (lane == p1) vv = -3e38f;
    }
    float sv = (lane < FK) ? myv : -3e38f;
    float mx = sv;
#pragma unroll
    for (int off = 8; off > 0; off >>= 1) mx = fmaxf(mx, __shfl_xor(mx, off, 16));
    float e = (lane < FK) ? expf(sv - mx) : 0.f;
    float se = e;
#pragma unroll
    for (int off = 8; off > 0; off >>= 1) se += __shfl_xor(se, off, 16);
    if (lane < FK) { wts[lane] = e / se; fidx[lane] = gix[myp]; }
  }
  __syncthreads();
  float4 a = make_float4(0.f, 0.f, 0.f, 0.f);
#pragma unroll
  for (int f = 0; f < FK; f++) {
    const float wt = wts[f];
    const float4 v = *reinterpret_cast<const float4*>(&Vall[(size_t)fidx[f] * DIM + tid * 4]);
    a.x = fmaf(wt, v.x, a.x);
    a.y = fmaf(wt, v.y, a.y);
    a.z = fmaf(wt, v.z, a.z);
    a.w = fmaf(wt, v.w, a.w);
  }
  *reinterpret_cast<float4*>(&out[(size_t)t * DIM + tid * 4]) = a;
}

// ---------------------------------------------------------------------------

extern "C" void kernel_launch(void* const* d_in, const int* in_sizes, int n_in,
                              void* d_out, int out_size, void* d_ws, size_t ws_size,
                              hipStream_t stream) {
  const float* x = (const float*)d_in[0];      // [4096][1024]
  const float* Wr = (const float*)d_in[1];     // [1024][65536]
  const float* Wenc = (const float*)d_in[2];   // [1024][128]
  const float* Kall = (const float*)d_in[3];   // [65536][128]
  const float* Vall = (const float*)d_in[4];   // [65536][1024]
  float* out = (float*)d_out;                  // [4096][1024]

  char* ws = (char*)d_ws;
  constexpr size_t OFF_WT = 0;                  // fp32 W^T    256 MB (live until pickscore)
  constexpr size_t OFF_WTB = 268435456;         // bf16 W^T    128 MB (dead after gemm)
  constexpr size_t OFF_XB = 402653184;          // bf16 x        8 MB (dead after gemm)
  constexpr size_t OFF_LG = 411041792;          // bf16 logits 512 MB
  constexpr size_t OFF_CMAX = 947912704;        // chunk-max keys 4 MB
  float* WT = (float*)(ws + OFF_WT);
  unsigned short* WTb = (unsigned short*)(ws + OFF_WTB);
  unsigned short* xb = (unsigned short*)(ws + OFF_XB);
  unsigned short* Lg = (unsigned short*)(ws + OFF_LG);
  unsigned short* CmaxT = (unsigned short*)(ws + OFF_CMAX);
  int* coarse = (int*)(ws + OFF_XB);            // 320 KB, aliases dead xb region

  k_transpose<<<65536, 256, 0, stream>>>(Wr, WT, WTb);
  k_cvt_x<<<4096, 256, 0, stream>>>(x, xb);
  k_gemm<<<8192, 512, 0, stream>>>(xb, WTb, Lg, CmaxT);
  k_pickscore<<<4096, 256, 0, stream>>>(CmaxT, Lg, x, WT, coarse);
  k_fine<<<4096, 256, 0, stream>>>(x, Wenc, Kall, Vall, coarse, out);
}

// Round 13
// 1048.401 us; speedup vs baseline: 1.1154x; 1.1154x over previous
//
#include <hip/hip_runtime.h>

#define DIM 1024
#define NKN 65536
#define TOK 4096
#define CK 20
#define FK 10
#define RNK 128
#define CAP 256
#define NCHUNK 512   // 65536 / 128 cols per GEMM block

typedef __bf16 v8bf __attribute__((ext_vector_type(8)));
typedef float v4f __attribute__((ext_vector_type(4)));

#define AS1 __attribute__((address_space(1)))
#define AS3 __attribute__((address_space(3)))

__device__ __forceinline__ unsigned short f2bf(float f) {
  // round-to-nearest-even fp32 -> bf16 (finite inputs only)
  unsigned u = __builtin_bit_cast(unsigned, f);
  u += 0x7FFFu + ((u >> 16) & 1u);
  return (unsigned short)(u >> 16);
}
__device__ __forceinline__ unsigned short bf2key(unsigned short b) {
  // monotone order-preserving key for bf16 bits
  return (b & 0x8000) ? (unsigned short)(~b) : (unsigned short)(b | 0x8000);
}

// ---------------------------------------------------------------------------
// K1: transpose W_router [DIM][NKN] -> WT fp32 [NKN][DIM] + WT bf16 [NKN][DIM]
// ---------------------------------------------------------------------------
__global__ __launch_bounds__(256) void k_transpose(const float* __restrict__ W,
                                                   float* __restrict__ WT,
                                                   unsigned short* __restrict__ WTb) {
  __shared__ float tile[32][33];
  const int n0 = (blockIdx.x & 2047) << 5;
  const int d0 = (blockIdx.x >> 11) << 5;
  const int c = threadIdx.x & 31, r0 = threadIdx.x >> 5;
#pragma unroll
  for (int i = 0; i < 4; i++) {
    int r = r0 + i * 8;
    tile[r][c] = W[(size_t)(d0 + r) * NKN + n0 + c];
  }
  __syncthreads();
#pragma unroll
  for (int i = 0; i < 4; i++) {
    int r = r0 + i * 8;
    float v = tile[c][r];  // = W[d0+c][n0+r]
    size_t o = (size_t)(n0 + r) * DIM + d0 + c;
    WT[o] = v;
    WTb[o] = f2bf(v);
  }
}

// ---------------------------------------------------------------------------
// K1b: convert x fp32 -> bf16
// ---------------------------------------------------------------------------
__global__ __launch_bounds__(256) void k_cvt_x(const float* __restrict__ x,
                                               unsigned short* __restrict__ xb) {
  const int i = blockIdx.x * 256 + threadIdx.x;
  const float4 v = reinterpret_cast<const float4*>(x)[i];
  ushort4 o;
  o.x = f2bf(v.x); o.y = f2bf(v.y); o.z = f2bf(v.z); o.w = f2bf(v.w);
  reinterpret_cast<ushort4*>(xb)[i] = o;
}

// ---------------------------------------------------------------------------
// K2: bf16 MFMA GEMM (r9 geometry), single barrier/tile, STAGE AFTER barrier
// (r13 — fixes r12's race).
// 256x128 tile, BK=32, 512 threads = 8 waves (4M x 2N), per-wave C = 64x64,
// acc 64 AGPR + ~60 VGPR -> 4 waves/SIMD = 2 blocks/CU. LDS: 3-slot ring x
// 24 KB.
// Tile order: vmcnt(3) -> s_barrier -> STAGE((T+2)%3) -> ds_reads(T%3) ->
// MFMA. r12's race: STAGE was issued BEFORE the barrier, so a fast wave's
// STAGE into slot t%3 (at tile t+1) overlapped a slow wave's reads of the
// same slot (at tile t). With STAGE after the barrier: the barrier is
// collective, so when any wave issues STAGE(slot t%3) at tile t+1, every
// wave has reached barrier(t+1), and its reads of slot t%3 (tile t) were
// lgkmcnt-consumed by its tile-t MFMAs before the barrier. Waves may still
// skew within (barrier .. next barrier), overlapping LDS reads of one wave
// with MFMA of another — the pipe overlap the double-barrier lockstep
// prevented (MFMA 41% + LDS ~50% were serializing to ~91% of tile period).
// vmcnt: prologue stages slots 0,1 (6 loads); steady vmcnt(3) retires the
// stage from 2 tiles ago (slot being read), newest stage stays in flight.
// LDS swizzle (r9, measured 0 conflicts): phys 16B-slot = lq ^ ((row>>1)&3);
// each aligned 8-lane group covers all 8 bank-quads. Rule-21: linear
// gload_lds dest + inverse-permuted global src + same perm on ds_read.
// Fused epilogue: per-row max over the block's 128 cols -> CmaxT[nb][row].
// ---------------------------------------------------------------------------
__global__ __launch_bounds__(512, 4) void k_gemm(const unsigned short* __restrict__ A,
                                                 const unsigned short* __restrict__ Bt,
                                                 unsigned short* __restrict__ Lg,
                                                 unsigned short* __restrict__ CmaxT) {
  __shared__ __align__(16) char lds[73728];  // ring[3]: {A 16 KB, B 8 KB}
  const int tid = threadIdx.x;
  const int lane = tid & 63, wid = tid >> 6;
  const int wm = wid >> 1, wn = wid & 1;
  const int mb = blockIdx.x & 15, nb = blockIdx.x >> 4;  // m-fast: B-panel reuse
  const int m0 = mb << 8, n0 = nb << 7;
  const int rm = lane & 15, lq = lane >> 4;
  v4f acc[4][4] = {};

  const int u8 = (((tid & 3) ^ ((tid >> 3) & 3)) << 3);
  const unsigned short* aSrc = A + (size_t)(m0 + (tid >> 2)) * DIM + u8;
  const unsigned short* bSrc = Bt + (size_t)(n0 + (tid >> 2)) * DIM + u8;

  const int sx = ((lq ^ ((rm >> 1) & 3)) << 4);
  const int aOff = (wm * 64 + rm) * 64 + sx;           // + fr*1024
  const int bOff = 16384 + (wn * 64 + rm) * 64 + sx;   // + nf*1024

#define STAGE(SLOT, KT) do { \
    char* _b = lds + (SLOT) * 24576 + tid * 16; \
    __builtin_amdgcn_global_load_lds((const AS1 void*)(aSrc + (KT)),             (AS3 void*)(_b),         16, 0, 0); \
    __builtin_amdgcn_global_load_lds((const AS1 void*)(aSrc + (KT) + 128 * DIM), (AS3 void*)(_b + 8192),  16, 0, 0); \
    __builtin_amdgcn_global_load_lds((const AS1 void*)(bSrc + (KT)),             (AS3 void*)(_b + 16384), 16, 0, 0); \
  } while (0)

#define TILE(T, VM, DOSTAGE) do { \
    asm volatile("s_waitcnt vmcnt(" VM ")" ::: "memory"); \
    __builtin_amdgcn_s_barrier(); \
    if (DOSTAGE) STAGE(((T) + 2) % 3, ((T) + 2) * 32); \
    const char* sb = lds + ((T) % 3) * 24576; \
    v8bf a0 = *(const v8bf*)(sb + aOff); \
    v8bf a1 = *(const v8bf*)(sb + aOff + 1024); \
    v8bf a2 = *(const v8bf*)(sb + aOff + 2048); \
    v8bf a3 = *(const v8bf*)(sb + aOff + 3072); \
    v8bf b0 = *(const v8bf*)(sb + bOff); \
    v8bf b1 = *(const v8bf*)(sb + bOff + 1024); \
    v8bf b2 = *(const v8bf*)(sb + bOff + 2048); \
    v8bf b3 = *(const v8bf*)(sb + bOff + 3072); \
    __builtin_amdgcn_s_setprio(1); \
    _Pragma("unroll") for (int nf = 0; nf < 4; ++nf) { \
      v8bf bb = (nf == 0) ? b0 : (nf == 1) ? b1 : (nf == 2) ? b2 : b3; \
      acc[0][nf] = __builtin_amdgcn_mfma_f32_16x16x32_bf16(a0, bb, acc[0][nf], 0, 0, 0); \
      acc[1][nf] = __builtin_amdgcn_mfma_f32_16x16x32_bf16(a1, bb, acc[1][nf], 0, 0, 0); \
      acc[2][nf] = __builtin_amdgcn_mfma_f32_16x16x32_bf16(a2, bb, acc[2][nf], 0, 0, 0); \
      acc[3][nf] = __builtin_amdgcn_mfma_f32_16x16x32_bf16(a3, bb, acc[3][nf], 0, 0, 0); \
    } \
    __builtin_amdgcn_s_setprio(0); \
  } while (0)

  // prologue: stage tiles 0,1 (6 loads in flight)
  STAGE(0, 0);
  STAGE(1, 32);

  // steady state: vmcnt(3) retires the slot staged 2 tiles ago (= slot read
  // this tile); the stage issued last tile stays in flight.
  for (int t = 0; t < 30; ++t) {
    TILE(t, "3", true);          // stages kt=(t+2)*32, last at t=29 -> 992
  }
  TILE(30, "3", false);
  TILE(31, "0", false);
#undef TILE
#undef STAGE

  // ---- epilogue ----
  // C/D layout (verified m89/m91): n = rm, m = lq*4 + reg
  const int mr = lq * 4;
  float rmax[4][4];
#pragma unroll
  for (int fr = 0; fr < 4; ++fr) {
#pragma unroll
    for (int r = 0; r < 4; ++r) {
      float mx = acc[fr][0][r];
#pragma unroll
      for (int nf = 1; nf < 4; ++nf) mx = fmaxf(mx, acc[fr][nf][r]);
      rmax[fr][r] = mx;
    }
#pragma unroll
    for (int nf = 0; nf < 4; ++nf) {
      const int mrow = m0 + wm * 64 + fr * 16 + mr;
      const int ncol = n0 + wn * 64 + nf * 16 + rm;
#pragma unroll
      for (int r = 0; r < 4; ++r)
        Lg[(size_t)(mrow + r) * NKN + ncol] = f2bf(acc[fr][nf][r]);
    }
  }
#pragma unroll
  for (int fr = 0; fr < 4; ++fr)
#pragma unroll
    for (int r = 0; r < 4; ++r) {
#pragma unroll
      for (int off = 1; off < 16; off <<= 1)
        rmax[fr][r] = fmaxf(rmax[fr][r], __shfl_xor(rmax[fr][r], off));
    }
  __syncthreads();
  float* smax = (float*)lds;  // [2][256]
  if (rm == 0) {
#pragma unroll
    for (int fr = 0; fr < 4; ++fr)
#pragma unroll
      for (int r = 0; r < 4; ++r)
        smax[wn * 256 + wm * 64 + fr * 16 + mr + r] = rmax[fr][r];
  }
  __syncthreads();
  if (tid < 256) {
    float v = fmaxf(smax[tid], smax[256 + tid]);
    CmaxT[(size_t)nb * TOK + m0 + tid] = bf2key(f2bf(v));
  }
}

// ---------------------------------------------------------------------------
// K3 (fused): pick candidates from chunk maxes + exact fp64 rescore + exact
// top-20. tau = 32nd-largest chunk-max key (exact); candidate set =
// {key >= tau} superset of bf16-top-32 superset of fp32-top-20.
// ---------------------------------------------------------------------------
__global__ __launch_bounds__(256) void k_pickscore(const unsigned short* __restrict__ CmaxT,
                                                   const unsigned short* __restrict__ Lg,
                                                   const float* __restrict__ x,
                                                   const float* __restrict__ WT,
                                                   int* __restrict__ coarse) {
  __shared__ unsigned short keys[NCHUNK];
  __shared__ int qlist[NCHUNK];
  __shared__ float xs[DIM];
  __shared__ double sc[CAP];
  __shared__ int ci[CAP];
  __shared__ int qn, scnt, bsS;
  const int t = blockIdx.x, tid = threadIdx.x;
  const int lane = tid & 63, w = tid >> 6;
  keys[tid] = CmaxT[(size_t)tid * TOK + t];
  keys[tid + 256] = CmaxT[(size_t)(tid + 256) * TOK + t];
  for (int i = tid; i < DIM; i += 256) xs[i] = x[(size_t)t * DIM + i];
  if (tid == 0) { qn = 0; scnt = 0; }
  __syncthreads();
  if (w == 0) {
    int v[8];
#pragma unroll
    for (int j = 0; j < 8; j++) v[j] = keys[lane * 8 + j];
    int t32 = 0;
    for (int it = 0; it < 32; it++) {
      int lm = v[0];
#pragma unroll
      for (int j = 1; j < 8; j++) lm = max(lm, v[j]);
      int gm = lm;
#pragma unroll
      for (int off = 32; off > 0; off >>= 1) gm = max(gm, __shfl_xor(gm, off));
      unsigned long long msk = __ballot(lm == gm);
      if (lane == __ffsll((long long)msk) - 1) {
        bool done = false;
#pragma unroll
        for (int j = 0; j < 8; j++)
          if (!done && v[j] == gm) { v[j] = -1; done = true; }
      }
      t32 = gm;
    }
    if (lane == 0) bsS = t32;
  }
  __syncthreads();
  const int bs = bsS;
  for (int c = tid; c < NCHUNK; c += 256)
    if ((int)keys[c] >= bs) { int p = atomicAdd(&qn, 1); qlist[p] = c; }
  __syncthreads();
  const int nq = qn;
  const int sub = tid >> 7, e = tid & 127;
  for (int qi = sub; qi < nq; qi += 2) {
    const int col = qlist[qi] * 128 + e;
    unsigned short key = bf2key(Lg[(size_t)t * NKN + col]);
    if ((int)key >= bs) {
      int p = atomicAdd(&scnt, 1);
      if (p < CAP) ci[p] = col;
    }
  }
  __syncthreads();
  const int cnt = min(scnt, CAP);
  for (int i = tid; i < CAP; i += 256)
    if (i >= cnt) ci[i] = 0;
  for (int i = tid; i < CAP; i += 256) sc[i] = -1e300;
  __syncthreads();
  for (int c = w; c < cnt; c += 4) {
    const float* wr = WT + (size_t)ci[c] * DIM;
    double sacc = 0.0;
#pragma unroll 4
    for (int i = lane; i < DIM; i += 64) sacc += (double)xs[i] * (double)wr[i];
#pragma unroll
    for (int off = 32; off > 0; off >>= 1) sacc += __shfl_down(sacc, off);
    if (lane == 0) sc[c] = sacc;
  }
  __syncthreads();
  if (w == 0) {
    double v[4];
    int ix[4];
#pragma unroll
    for (int j = 0; j < 4; j++) { v[j] = sc[lane + j * 64]; ix[j] = lane + j * 64; }
    for (int kk = 0; kk < CK; kk++) {
      double v1 = v[0]; int i1 = ix[0];
#pragma unroll
      for (int j = 1; j < 4; j++)
        if (v[j] > v1) { v1 = v[j]; i1 = ix[j]; }
#pragma unroll
      for (int off = 32; off > 0; off >>= 1) {
        double ov = __shfl_down(v1, off);
        int oi = __shfl_down(i1, off);
        if (ov > v1) { v1 = ov; i1 = oi; }
      }
      i1 = __shfl(i1, 0);
      if (lane == 0) coarse[(size_t)t * CK + kk] = ci[i1];
#pragma unroll
      for (int j = 0; j < 4; j++)
        if (i1 == ix[j]) v[j] = -1e300;
    }
  }
}

// ---------------------------------------------------------------------------
// K4 (fused): query = x @ W_enc in-kernel, then fine scores vs 20 candidates,
// top-10, softmax, weighted V blend.
// ---------------------------------------------------------------------------
__global__ __launch_bounds__(256) void k_fine(const float* __restrict__ x,
                                              const float* __restrict__ Wenc,
                                              const float* __restrict__ Kall,
                                              const float* __restrict__ Vall,
                                              const int* __restrict__ coarse,
                                              float* __restrict__ out) {
  __shared__ float xs[DIM];
  __shared__ float pq[2][RNK];
  __shared__ float qs[RNK];
  __shared__ float fsc[CK];
  __shared__ int gix[CK];
  __shared__ float wts[FK];
  __shared__ int fidx[FK];
  const int t = blockIdx.x, tid = threadIdx.x;
  const int lane = tid & 63, w = tid >> 6;
  reinterpret_cast<float4*>(xs)[tid] = reinterpret_cast<const float4*>(x + (size_t)t * DIM)[tid];
  if (tid < CK) gix[tid] = coarse[(size_t)t * CK + tid];
  __syncthreads();
  {
    const int j = tid & 127, half = tid >> 7;
    float s = 0.f;
    const int d0 = half * 512;
#pragma unroll 8
    for (int d = 0; d < 512; d++)
      s = fmaf(xs[d0 + d], Wenc[(size_t)(d0 + d) * RNK + j], s);
    pq[half][j] = s;
  }
  __syncthreads();
  if (tid < RNK) qs[tid] = pq[0][tid] + pq[1][tid];
  __syncthreads();
  for (int c = w; c < CK; c += 4) {
    const float* kr = Kall + (size_t)gix[c] * RNK;
    float s = 0.f;
    s = fmaf(qs[lane], kr[lane], s);
    s = fmaf(qs[lane + 64], kr[lane + 64], s);
#pragma unroll
    for (int off = 32; off > 0; off >>= 1) s += __shfl_down(s, off);
    if (lane == 0) fsc[c] = s * 0.08838834764831843f;  // 1/sqrt(128)
  }
  __syncthreads();
  if (w == 0) {
    float vv = (lane < CK) ? fsc[lane] : -3e38f;
    float myv = -3e38f; int myp = 0;
    for (int kk = 0; kk < FK; kk++) {
      float v1 = vv; int p1 = lane;
#pragma unroll
      for (int off = 32; off > 0; off >>= 1) {
        float ov = __shfl_down(v1, off);
        int op = __shfl_down(p1, off);
        if (ov > v1) { v1 = ov; p1 = op; }
      }
      v1 = __shfl(v1, 0); p1 = __shfl(p1, 0);
      if (lane == kk) { myv = v1; myp = p1; }
      if (lane == p1) vv = -3e38f;
    }
    float sv = (lane < FK) ? myv : -3e38f;
    float mx = sv;
#pragma unroll
    for (int off = 8; off > 0; off >>= 1) mx = fmaxf(mx, __shfl_xor(mx, off, 16));
    float e = (lane < FK) ? expf(sv - mx) : 0.f;
    float se = e;
#pragma unroll
    for (int off = 8; off > 0; off >>= 1) se += __shfl_xor(se, off, 16);
    if (lane < FK) { wts[lane] = e / se; fidx[lane] = gix[myp]; }
  }
  __syncthreads();
  float4 a = make_float4(0.f, 0.f, 0.f, 0.f);
#pragma unroll
  for (int f = 0; f < FK; f++) {
    const float wt = wts[f];
    const float4 v = *reinterpret_cast<const float4*>(&Vall[(size_t)fidx[f] * DIM + tid * 4]);
    a.x = fmaf(wt, v.x, a.x);
    a.y = fmaf(wt, v.y, a.y);
    a.z = fmaf(wt, v.z, a.z);
    a.w = fmaf(wt, v.w, a.w);
  }
  *reinterpret_cast<float4*>(&out[(size_t)t * DIM + tid * 4]) = a;
}

// ---------------------------------------------------------------------------

extern "C" void kernel_launch(void* const* d_in, const int* in_sizes, int n_in,
                              void* d_out, int out_size, void* d_ws, size_t ws_size,
                              hipStream_t stream) {
  const float* x = (const float*)d_in[0];      // [4096][1024]
  const float* Wr = (const float*)d_in[1];     // [1024][65536]
  const float* Wenc = (const float*)d_in[2];   // [1024][128]
  const float* Kall = (const float*)d_in[3];   // [65536][128]
  const float* Vall = (const float*)d_in[4];   // [65536][1024]
  float* out = (float*)d_out;                  // [4096][1024]

  char* ws = (char*)d_ws;
  constexpr size_t OFF_WT = 0;                  // fp32 W^T    256 MB (live until pickscore)
  constexpr size_t OFF_WTB = 268435456;         // bf16 W^T    128 MB (dead after gemm)
  constexpr size_t OFF_XB = 402653184;          // bf16 x        8 MB (dead after gemm)
  constexpr size_t OFF_LG = 411041792;          // bf16 logits 512 MB
  constexpr size_t OFF_CMAX = 947912704;        // chunk-max keys 4 MB
  float* WT = (float*)(ws + OFF_WT);
  unsigned short* WTb = (unsigned short*)(ws + OFF_WTB);
  unsigned short* xb = (unsigned short*)(ws + OFF_XB);
  unsigned short* Lg = (unsigned short*)(ws + OFF_LG);
  unsigned short* CmaxT = (unsigned short*)(ws + OFF_CMAX);
  int* coarse = (int*)(ws + OFF_XB);            // 320 KB, aliases dead xb region

  k_transpose<<<65536, 256, 0, stream>>>(Wr, WT, WTb);
  k_cvt_x<<<4096, 256, 0, stream>>>(x, xb);
  k_gemm<<<8192, 512, 0, stream>>>(xb, WTb, Lg, CmaxT);
  k_pickscore<<<4096, 256, 0, stream>>>(CmaxT, Lg, x, WT, coarse);
  k_fine<<<4096, 256, 0, stream>>>(x, Wenc, Kall, Vall, coarse, out);
}